// Round 8
// baseline (271.877 us; speedup 1.0000x reference)
//
#include <hip/hip_runtime.h>

// SSIM (window=8 box sums) over 96 images of 512x512 fp32.
// v13 = v12 + depth-2 OUTGOING stream (the vmcnt fix):
//  - v12 post-mortem: depth-2 incoming was NULL (124 vs 120 us).  Cause:
//    vmcnt is a counter, not per-reg scoreboard.  Outgoing row issued at
//    iter i, consumed at i+1, is the YOUNGEST outstanding load -> its
//    consume forces vmcnt(0) = full drain, collapsing the incoming
//    ping-pong back to depth-1.
//  - v13: outgoing also ping-pongs (PA/PB): issue row o+1 at iter o,
//    consume at o+2.  Consumed loads are now one full iteration older
//    than the youngest outstanding -> compiler emits counted vmcnt(~8),
//    every load gets ~2 row-times of flight.
//  - __launch_bounds__(64) (no min): +16 VGPR state breaks the (64,2)
//    cap of 128 (v12 pinned at exactly 128).  Cap 256; expected ~150 ->
//    3 waves/SIMD = exactly the grid's 12 waves/CU.
//  - keep TH=16, 64-thread waves, XCD swizzle (all held fixed).
// Tripwires: WRITE_SIZE >> 96 KB => spill; VGPR <= ~170 for 3 waves/SIMD.

#define W 512
#define H 512
#define OW 505
#define OH 505
#define TH 16
#define NSTRIP ((OH + TH - 1) / TH)   // 32
#define NIMG 96
#define NWG (NSTRIP * NIMG)           // 3072, divisible by 8
#define NPIX (96.0 * 505.0 * 505.0)   // 24482400

__device__ __forceinline__ float4 ld4(const float* p) { return *(const float4*)p; }

__global__ void finalize(const double* p, float* out) {
    out[0] = 1.0f - (float)(*p / NPIX);
}

// unpack two float4s into a float[8]
#define UNPACK8(a0, a1, dst) {                                            \
        dst[0] = a0.x; dst[1] = a0.y; dst[2] = a0.z; dst[3] = a0.w;       \
        dst[4] = a1.x; dst[5] = a1.y; dst[6] = a1.z; dst[7] = a1.w;       \
    }

__global__ void __launch_bounds__(64)
ssim_main(const float* __restrict__ gt, const float* __restrict__ ni,
          double* __restrict__ acc_out)
{
    const int l   = threadIdx.x;      // 0..63
    const int c0  = l * 8;            // own cols c0..c0+7

    // XCD-aware swizzle: HW assigns XCD = blockIdx % 8 (round-robin).
    // wid = xcd*384 + slot, strip-fastest: adjacent strips of one image run
    // on the SAME XCD -> strip-overlap re-reads hit that XCD's L2.
    const int b     = blockIdx.x;
    const int wid   = (b & 7) * (NWG / 8) + (b >> 3);
    const int strip = wid & (NSTRIP - 1);
    const int img   = wid >> 5;       // NSTRIP = 32

    const int R0  = strip * TH;       // first output row of strip
    const int R1  = min(R0 + TH, OH); // >= 9 output rows per strip

    const float C1 = 1e-4f;
    const float C2 = 9e-4f;

    const float* gx = gt + (size_t)img * (W * H) + c0;
    const float* gy = gt == ni ? gx : ni + (size_t)img * (W * H) + c0;

    // vertical 8-row window sums for own 8 columns
    float vsx[8], vsy[8], vsq[8], vsp[8];
#pragma unroll
    for (int j = 0; j < 8; ++j) { vsx[j] = 0.f; vsy[j] = 0.f; vsq[j] = 0.f; vsp[j] = 0.f; }

    // incoming ping-pong slots A/B; outgoing ping-pong slots PA/PB
    float4 ax0, ax1, ay0, ay1;
    float4 bx0, bx1, by0, by1;
    float4 pax0, pax1, pay0, pay1;
    float4 pbx0, pbx1, pby0, pby1;

    float acc = 0.0f;

#define ISSUE(X0, X1, Y0, Y1, row) {                                      \
        const float* p_ = gx + (size_t)(row) * W;                         \
        const float* q_ = gy + (size_t)(row) * W;                         \
        X0 = ld4(p_); X1 = ld4(p_ + 4);                                   \
        Y0 = ld4(q_); Y1 = ld4(q_ + 4);                                   \
    }

// warmup step: consume slot (row R0+roff), re-issue slot <- row R0+roff+2,
// accumulate add-only.  roff+2 <= 8 -> row <= R0+8 <= 504, always valid.
#define WARM(roff, X0, X1, Y0, Y1) {                                      \
        float cx[8], cy[8];                                               \
        UNPACK8(X0, X1, cx)                                               \
        UNPACK8(Y0, Y1, cy)                                               \
        ISSUE(X0, X1, Y0, Y1, R0 + (roff) + 2)                            \
        _Pragma("unroll")                                                 \
        for (int j = 0; j < 8; ++j) {                                     \
            vsx[j] = vsx[j] + cx[j];                                      \
            vsy[j] = vsy[j] + cy[j];                                      \
            vsq[j] = vsq[j] + (cx[j] * cx[j] + cy[j] * cy[j]);            \
            vsp[j] = vsp[j] + cx[j] * cy[j];                              \
        }                                                                 \
    }

// horizontal sliding window + SSIM for one output row; shuffles lane+1.
// lane 63's shuffle result is garbage but only feeds cols >= 505 (predicated).
#define HORIZ_SSIM() {                                                    \
        float nx[8], ny[8], nq[8], np_[8];                                \
        _Pragma("unroll")                                                 \
        for (int j = 0; j < 8; ++j) {                                     \
            nx[j]  = __shfl_down(vsx[j], 1);                              \
            ny[j]  = __shfl_down(vsy[j], 1);                              \
            nq[j]  = __shfl_down(vsq[j], 1);                              \
            np_[j] = __shfl_down(vsp[j], 1);                              \
        }                                                                 \
        float Sx = ((vsx[0] + vsx[1]) + (vsx[2] + vsx[3])) +              \
                   ((vsx[4] + vsx[5]) + (vsx[6] + vsx[7]));               \
        float Sy = ((vsy[0] + vsy[1]) + (vsy[2] + vsy[3])) +              \
                   ((vsy[4] + vsy[5]) + (vsy[6] + vsy[7]));               \
        float Sq = ((vsq[0] + vsq[1]) + (vsq[2] + vsq[3])) +              \
                   ((vsq[4] + vsq[5]) + (vsq[6] + vsq[7]));               \
        float Sp = ((vsp[0] + vsp[1]) + (vsp[2] + vsp[3])) +              \
                   ((vsp[4] + vsp[5]) + (vsp[6] + vsp[7]));               \
        _Pragma("unroll")                                                 \
        for (int j = 0; j < 8; ++j) {                                     \
            if (j) {                                                      \
                Sx += nx[j-1] - vsx[j-1];                                 \
                Sy += ny[j-1] - vsy[j-1];                                 \
                Sq += nq[j-1] - vsq[j-1];                                 \
                Sp += np_[j-1] - vsp[j-1];                                \
            }                                                             \
            float mu12 = Sx * Sy;                                         \
            float n1v = 2.0f * mu12 + C1;                                 \
            float n2v = 2.0f * (Sp - mu12) + C2;                          \
            float sx2 = Sx * Sx, sy2 = Sy * Sy;                           \
            float d1  = sx2 + sy2 + C1;                                   \
            float d2  = (Sq - sx2 - sy2) + C2;                            \
            float sv  = (n1v * n2v) * __builtin_amdgcn_rcpf(d1 * d2);     \
            if (c0 + j < OW) acc += sv;                                   \
        }                                                                 \
    }

// main-loop row: consume incoming slot (row o+7) + outgoing slot (row o-1);
// both were issued at iter o-2 -> compiler emits COUNTED vmcnt (only iter
// o-1's 8 loads may remain outstanding).  Re-issue: incoming <- row o+9
// (consumed at o+2), outgoing <- row o+1 (consumed at o+2).
#define ROWM(o, X0, X1, Y0, Y1, P0, P1, Q0, Q1) {                         \
        float cx[8], cy[8], ox[8], oy[8];                                 \
        UNPACK8(X0, X1, cx)                                               \
        UNPACK8(Y0, Y1, cy)                                               \
        UNPACK8(P0, P1, ox)                                               \
        UNPACK8(Q0, Q1, oy)                                               \
        if ((o) + 2 < R1) {                                               \
            ISSUE(X0, X1, Y0, Y1, (o) + 9)                                \
            ISSUE(P0, P1, Q0, Q1, (o) + 1)                                \
        }                                                                 \
        _Pragma("unroll")                                                 \
        for (int j = 0; j < 8; ++j) {                                     \
            vsx[j] = (vsx[j] - ox[j]) + cx[j];                            \
            vsy[j] = (vsy[j] - oy[j]) + cy[j];                            \
            vsq[j] = vsq[j] + ((cx[j] * cx[j] + cy[j] * cy[j]) -          \
                               (ox[j] * ox[j] + oy[j] * oy[j]));          \
            vsp[j] = vsp[j] + (cx[j] * cy[j] - ox[j] * oy[j]);            \
        }                                                                 \
        HORIZ_SSIM()                                                      \
    }

    // prime pipeline: A = row R0, B = row R0+1
    ISSUE(ax0, ax1, ay0, ay1, R0)
    ISSUE(bx0, bx1, by0, by1, R0 + 1)

    // warmup rows R0..R0+6 (roles alternate A,B,A,B,A,B,A)
    WARM(0, ax0, ax1, ay0, ay1)
    WARM(1, bx0, bx1, by0, by1)
    WARM(2, ax0, ax1, ay0, ay1)
    WARM(3, bx0, bx1, by0, by1)
    WARM(4, ax0, ax1, ay0, ay1)
    WARM(5, bx0, bx1, by0, by1)   // issues B <- row R0+7
    WARM(6, ax0, ax1, ay0, ay1)   // issues A <- row R0+8
    // now: B = row R0+7 (ready), A = row R0+8 (in flight)

    // first output row o = R0: consume B (row R0+7), add-only.
    // Prime: B <- row R0+9 (for o=R0+2), PA <- row R0 (for o=R0+1),
    //        PB <- row R0+1 (for o=R0+2).  All guards trivially true
    //        (every strip has >= 9 output rows).
    {
        float cx[8], cy[8];
        UNPACK8(bx0, bx1, cx)
        UNPACK8(by0, by1, cy)
        ISSUE(bx0, bx1, by0, by1, R0 + 9)
        ISSUE(pax0, pax1, pay0, pay1, R0)
        ISSUE(pbx0, pbx1, pby0, pby1, R0 + 1)
#pragma unroll
        for (int j = 0; j < 8; ++j) {
            vsx[j] = vsx[j] + cx[j];
            vsy[j] = vsy[j] + cy[j];
            vsq[j] = vsq[j] + (cx[j] * cx[j] + cy[j] * cy[j]);
            vsp[j] = vsp[j] + cx[j] * cy[j];
        }
        HORIZ_SSIM()
    }

    // main loop: o = R0+1 .. R1-1.  Parity: odd (o-R0) -> A/PA, even -> B/PB.
    // Max issued row: o+9 with o+2 < R1 <= 505 -> o <= 502 -> row <= 511, OK.
    {
        int o = R0 + 1;
        while (o + 1 < R1) {
            ROWM(o,     ax0, ax1, ay0, ay1, pax0, pax1, pay0, pay1)
            ROWM(o + 1, bx0, bx1, by0, by1, pbx0, pbx1, pby0, pby1)
            o += 2;
        }
        if (o < R1) {
            ROWM(o, ax0, ax1, ay0, ay1, pax0, pax1, pay0, pay1)
        }
    }

    // ---- reduction: single wave -> one double atomic ----
#pragma unroll
    for (int off = 32; off > 0; off >>= 1) acc += __shfl_down(acc, off);
    if (l == 0) atomicAdd(acc_out, (double)acc);
}

extern "C" void kernel_launch(void* const* d_in, const int* in_sizes, int n_in,
                              void* d_out, int out_size, void* d_ws, size_t ws_size,
                              hipStream_t stream) {
    const float* gt = (const float*)d_in[0];
    const float* ni = (const float*)d_in[1];
    double* acc = (double*)d_ws;   // 8 bytes scratch, re-poisoned every call

    hipMemsetAsync(acc, 0, sizeof(double), stream);
    ssim_main<<<dim3(NWG), 64, 0, stream>>>(gt, ni, acc);
    finalize<<<1, 1, 0, stream>>>(acc, (float*)d_out);
}

// Round 9
// 227.295 us; speedup vs baseline: 1.1961x; 1.1961x over previous
//
#include <hip/hip_runtime.h>

// SSIM (window=8 box sums) over 96 images of 512x512 fp32.
// v14 = v8 EXACTLY (the best-measured kernel, 94.4 us) with TH 16 -> 64.
//  - v11/v12/v13 post-mortem: three latency-structure attacks (2x TLP,
//    depth-2 incoming ILP, depth-2 both-stream ILP) all NULL.  Unifying
//    model: time ~= delivered bytes / (~3-4 TB/s L1-miss service rate):
//    v8 283MB/94us=3.0, v10 467MB/120us=3.9, v11 540MB/129=4.2,
//    v12 467/124=3.8, v13 467/133=3.5 TB/s.  All on the same roofline;
//    the outgoing-re-read versions lose on BYTES, not latency.
//  - Lever: cut delivered bytes.  v8's ring already reads each row once
//    per strip; the residual redundancy is strip overlap (23 rows read
//    per 16 output rows).  TH=64: 71 rows per 64 output rows -> 216 MB
//    total (vs 283).  Grid 8x96=768 blocks (1536 waves, 6/CU) -- v11
//    proved extra TLP buys nothing, so the smaller grid should be safe.
//  - Everything else byte-identical to v8 (LDS 2-slot, lgkmcnt barriers,
//    (128,2) launch bounds, 2D grid).
// Tripwires: WRITE_SIZE >> 96 KB => spill; VGPR ~72 expected.

#define W 512
#define H 512
#define OW 505
#define OH 505
#define TH 64
#define NSTRIP ((OH + TH - 1) / TH)   // 8
#define NIMG 96
#define NPIX (96.0 * 505.0 * 505.0)   // 24482400

__device__ __forceinline__ float4 ld4(const float* p) { return *(const float4*)p; }
__device__ __forceinline__ float4 f4add(float4 a, float4 b) {
    return make_float4(a.x + b.x, a.y + b.y, a.z + b.z, a.w + b.w);
}
__device__ __forceinline__ float4 f4sub(float4 a, float4 b) {
    return make_float4(a.x - b.x, a.y - b.y, a.z - b.z, a.w - b.w);
}
__device__ __forceinline__ float4 f4mul(float4 a, float4 b) {
    return make_float4(a.x * b.x, a.y * b.y, a.z * b.z, a.w * b.w);
}

// LDS-only barrier: order this wave's ds ops, then sync the block.
// Deliberately NOT __syncthreads(): that drains vmcnt(0) and would kill the
// global prefetch loads' flight across the barrier.
__device__ __forceinline__ void wbar() {
    asm volatile("s_waitcnt lgkmcnt(0)" ::: "memory");
    __builtin_amdgcn_s_barrier();
}

__global__ void finalize(const double* p, float* out) {
    out[0] = 1.0f - (float)(*p / NPIX);
}

__global__ void __launch_bounds__(128, 2)
ssim_main(const float* __restrict__ gt, const float* __restrict__ ni,
          double* __restrict__ acc_out)
{
    const int t   = threadIdx.x;      // 0..127
    const int c0  = t * 4;            // base column (0..508)
    const int img = blockIdx.y;
    const int R0  = blockIdx.x * TH;  // first output row of strip (mult of 8)
    const int R1  = min(R0 + TH, OH);

    const float C1 = 1e-4f;
    const float C2 = 9e-4f;

    const float* gx = gt + (size_t)img * (W * H) + c0;
    const float* gy = ni + (size_t)img * (W * H) + c0;

    // 2 row-slots x 4 quantities x 520 cols (width 520: threads 126/127 read
    // past col 511 -> garbage, predicated out of the accumulate).
    __shared__ float vbuf[2][4][520];
    __shared__ float wpart[2];

    float4 ring_x[8], ring_y[8];
    float4 vsx = make_float4(0, 0, 0, 0);   // sum x
    float4 vsy = make_float4(0, 0, 0, 0);   // sum y
    float4 vsq = make_float4(0, 0, 0, 0);   // sum x^2 + y^2
    float4 vsp = make_float4(0, 0, 0, 0);   // sum x*y

    // warm-up: rows R0..R0+6 -> ring slots 0..6; slot 7 = zeros
#pragma unroll
    for (int k = 0; k < 7; ++k) {
        float4 x = ld4(gx + (size_t)(R0 + k) * W);
        float4 y = ld4(gy + (size_t)(R0 + k) * W);
        ring_x[k] = x; ring_y[k] = y;
        vsx = f4add(vsx, x);
        vsy = f4add(vsy, y);
        vsq = f4add(vsq, f4add(f4mul(x, x), f4mul(y, y)));
        vsp = f4add(vsp, f4mul(x, y));
    }
    ring_x[7] = make_float4(0, 0, 0, 0);
    ring_y[7] = make_float4(0, 0, 0, 0);

    // prefetch rows R0+7, R0+8 (R0 <= 448 -> rows <= 456 < 512, always valid)
    float4 pfx[2], pfy[2];
    pfx[0] = ld4(gx + (size_t)(R0 + 7) * W);
    pfy[0] = ld4(gy + (size_t)(R0 + 7) * W);
    pfx[1] = ld4(gx + (size_t)(R0 + 8) * W);
    pfy[1] = ld4(gy + (size_t)(R0 + 8) * W);

    float acc = 0.0f;

// phase A, one row: consume prefetch slot m, slide vsums, publish LDS row m
#define PHASEA_ROW(rb, m, slot) {                                         \
        if ((rb) + (m) < R1) { /* block-uniform */                        \
            float4 cx = pfx[m], cy = pfy[m];                              \
            float4 ox = ring_x[slot], oy = ring_y[slot];                  \
            vsx = f4add(f4sub(vsx, ox), cx);                              \
            vsy = f4add(f4sub(vsy, oy), cy);                              \
            vsq = f4add(vsq, f4sub(f4add(f4mul(cx, cx), f4mul(cy, cy)),   \
                                   f4add(f4mul(ox, ox), f4mul(oy, oy)))); \
            vsp = f4add(vsp, f4sub(f4mul(cx, cy), f4mul(ox, oy)));        \
            ring_x[slot] = cx; ring_y[slot] = cy;                         \
            *(float4*)&vbuf[m][0][c0] = vsx;                              \
            *(float4*)&vbuf[m][1][c0] = vsy;                              \
            *(float4*)&vbuf[m][2][c0] = vsq;                              \
            *(float4*)&vbuf[m][3][c0] = vsp;                              \
        }                                                                 \
    }

// 8-wide horizontal sliding sums from 3 LDS float4s (own, +4, +8)
#define HORIZ(q) {                                                        \
        float4 o = *(float4*)&vbuf[m][q][c0];                             \
        float4 a = *(float4*)&vbuf[m][q][c0 + 4];                         \
        float4 e = *(float4*)&vbuf[m][q][c0 + 8];                         \
        float s = ((o.x + o.y) + (o.z + o.w)) +                           \
                  ((a.x + a.y) + (a.z + a.w));                            \
        B[q][0] = s;                                                      \
        s += e.x - o.x; B[q][1] = s;                                      \
        s += e.y - o.y; B[q][2] = s;                                      \
        s += e.z - o.z; B[q][3] = s;                                      \
    }

// phase B, one row: horizontal sums + SSIM + accumulate
#define PHASEB_ROW(rb, mm) {                                              \
        if ((rb) + (mm) < R1) { /* block-uniform */                       \
            const int m = (mm);                                           \
            float B[4][4];                                                \
            HORIZ(0) HORIZ(1) HORIZ(2) HORIZ(3)                           \
            _Pragma("unroll")                                             \
            for (int j = 0; j < 4; ++j) {                                 \
                float Sx = B[0][j], Sy = B[1][j];                         \
                float Sq = B[2][j], Sp = B[3][j];                         \
                float mu12 = Sx * Sy;                                     \
                float n1v = 2.0f * mu12 + C1;                             \
                float n2v = 2.0f * (Sp - mu12) + C2;                      \
                float sx2 = Sx * Sx, sy2 = Sy * Sy;                       \
                float d1  = sx2 + sy2 + C1;                               \
                float d2  = (Sq - sx2 - sy2) + C2;                        \
                float sv  = (n1v * n2v) * __builtin_amdgcn_rcpf(d1 * d2); \
                if (c0 + j < OW) acc += sv;                               \
            }                                                             \
        }                                                                 \
    }

// one group = 2 rows: phase A, bar, prefetch-issue, phase B, bar.
// prefetch rows (rb)+9,(rb)+10 are consumed as pfx[0],pfx[1] by group rb+2;
// guards (rb)+2+m < R1 match the consumer's (rb+2)+m < R1 exactly.
// max row read: (rb)+10 with (rb)+3 < R1 <= 505 -> row <= 511, in bounds.
#define GROUP2(rb, s0, s1) {                                              \
        if ((rb) < R1) { /* block-uniform */                              \
            PHASEA_ROW(rb, 0, s0) PHASEA_ROW(rb, 1, s1)                   \
            wbar();                                                       \
            if ((rb) + 2 < R1) {                                          \
                pfx[0] = ld4(gx + (size_t)((rb) + 9) * W);                \
                pfy[0] = ld4(gy + (size_t)((rb) + 9) * W);                \
            }                                                             \
            if ((rb) + 3 < R1) {                                          \
                pfx[1] = ld4(gx + (size_t)((rb) + 10) * W);               \
                pfy[1] = ld4(gy + (size_t)((rb) + 10) * W);               \
            }                                                             \
            PHASEB_ROW(rb, 0) PHASEB_ROW(rb, 1)                           \
            wbar();                                                       \
        }                                                                 \
    }

    // R0 mult of 8 -> ring slot for output row r is ((r-R0)+7)&7:
    // groups cycle slots (7,0),(1,2),(3,4),(5,6) per 8 rows.
    for (int rb0 = R0; rb0 < R1; rb0 += 8) {
        GROUP2(rb0,     7, 0)
        GROUP2(rb0 + 2, 1, 2)
        GROUP2(rb0 + 4, 3, 4)
        GROUP2(rb0 + 6, 5, 6)
    }

    // reduction: wave shuffle -> LDS -> one double atomic per block
#pragma unroll
    for (int off = 32; off > 0; off >>= 1) acc += __shfl_down(acc, off);
    const int wave = t >> 6, lane = t & 63;
    if (lane == 0) wpart[wave] = acc;
    __syncthreads();
    if (t == 0) atomicAdd(acc_out, (double)(wpart[0] + wpart[1]));
}

extern "C" void kernel_launch(void* const* d_in, const int* in_sizes, int n_in,
                              void* d_out, int out_size, void* d_ws, size_t ws_size,
                              hipStream_t stream) {
    const float* gt = (const float*)d_in[0];
    const float* ni = (const float*)d_in[1];
    double* acc = (double*)d_ws;   // 8 bytes scratch, re-poisoned every call

    hipMemsetAsync(acc, 0, sizeof(double), stream);
    dim3 grid(NSTRIP, NIMG);
    ssim_main<<<grid, 128, 0, stream>>>(gt, ni, acc);
    finalize<<<1, 1, 0, stream>>>(acc, (float*)d_out);
}